// Round 8
// baseline (675.923 us; speedup 1.0000x reference)
//
#include <hip/hip_runtime.h>
#include <math.h>

#define N_NODES 10240
#define DIM 256
#define TPB 256
#define CAP 1536

typedef _Float16 half8 __attribute__((ext_vector_type(8)));
typedef _Float16 half4 __attribute__((ext_vector_type(4)));
typedef float f32x16 __attribute__((ext_vector_type(16)));

__device__ __forceinline__ void async_load16(const void* g, void* l) {
  __builtin_amdgcn_global_load_lds(
      (const __attribute__((address_space(1))) unsigned int*)g,
      (__attribute__((address_space(3))) unsigned int*)l, 16, 0, 0);
}

// ---------------------------------------------------------------------------
// Kernel 1: one wave per row, barrier-free. float4 loads, 6-hop shfl_xor
// butterfly for ||h||^2, packed half4 stores (fp16x3 split: p1=(e-p0)*2^11).
// ---------------------------------------------------------------------------
__global__ __launch_bounds__(256) void norm_split_kernel(
    const float* __restrict__ F, const float* __restrict__ w1,
    const float* __restrict__ w2, _Float16* __restrict__ P0,
    _Float16* __restrict__ P1) {
  int wave = threadIdx.x >> 6;
  int lane = threadIdx.x & 63;
  int row = blockIdx.x * 4 + wave;
  size_t base = (size_t)row * DIM + lane * 4;

  float4 f = *(const float4*)&F[base];
  float4 a = *(const float4*)&w1[lane * 4];
  float4 b = *(const float4*)&w2[lane * 4];
  float h0 = fmaxf(f.x * a.x, 0.0f) * b.x;
  float h1 = fmaxf(f.y * a.y, 0.0f) * b.y;
  float h2 = fmaxf(f.z * a.z, 0.0f) * b.z;
  float h3 = fmaxf(f.w * a.w, 0.0f) * b.w;

  float ss = h0 * h0 + h1 * h1 + h2 * h2 + h3 * h3;
#pragma unroll
  for (int o = 1; o < 64; o <<= 1) ss += __shfl_xor(ss, o, 64);
  float inv = 1.0f / fmaxf(sqrtf(ss), 1e-12f);

  float e[4] = {h0 * inv, h1 * inv, h2 * inv, h3 * inv};
  half4 p0, p1;
#pragma unroll
  for (int c = 0; c < 4; ++c) {
    _Float16 hi = (_Float16)e[c];
    p0[c] = hi;
    p1[c] = (_Float16)((e[c] - (float)hi) * 2048.0f);
  }
  *(half4*)&P0[base] = p0;
  *(half4*)&P1[base] = p1;
}

// ---------------------------------------------------------------------------
// Kernel 2: C = E*E^T via fp16x3 MFMA — R3 structure (32KB LDS, 3 passes x
// 4 chunks, single accumulator; R4 mirror / R5 fusion / R6 digest all
// regressed), but with 32x32x16 MFMA instead of 16x16x32:
// same ds_read count (16 b128/chunk), same 64 acc VGPRs, but 16 MFMA x 8cyc
// = 128 cyc/chunk vs 32 x 4.8 = 154 — the 32x32 pipe runs at 2495 vs 2075 TF
// (m119/m06). Per-wave tile 64x64 = 2x2 tiles of 32x32, K=16 per MFMA.
// A-frag: row=lane&31, k=(lane>>5)*8+j. C/D (m74/m101): col=lane&31,
// row=(reg&3)+8*(reg>>2)+4*(lane>>5).
// ---------------------------------------------------------------------------
__global__ __launch_bounds__(256) void gemm_mfma_kernel(
    const _Float16* __restrict__ P0, const _Float16* __restrict__ P1,
    float* __restrict__ C) {
  __shared__ char smem[32768];
  char* AsB = smem;            // 128 rows x 64 halves (16 KB), swizzled
  char* BsB = smem + 16384;

  int tid = threadIdx.x;
  int lane = tid & 63;
  int w = tid >> 6;
  int wr = (w >> 1) * 64;      // wave row quadrant
  int wc = (w & 1) * 64;       // wave col quadrant
  int l31 = lane & 31;
  int lh = lane >> 5;          // k-half selector
  int rowBase = blockIdx.y * 128;
  int colBase = blockIdx.x * 128;

  // staging: 4 16B units per thread per tile (1024 units = 16KB tile)
  size_t rowOffA[4], rowOffB[4];
  int ldsOff[4];
#pragma unroll
  for (int i = 0; i < 4; ++i) {
    int u = tid + i * 256;
    int m = u >> 3;
    int g = (u & 7) ^ (m & 7);
    ldsOff[i] = u * 16;
    rowOffA[i] = (size_t)(rowBase + m) * DIM + g * 8;
    rowOffB[i] = (size_t)(colBase + m) * DIM + g * 8;
  }

  // fragment ds_read byte offsets: [kstep s 0..3][tile t 0..1]
  // row m needs k = s*16 + lh*8 .. +8  ->  k-group g = s*2 + lh
  int fOffA[4][2], fOffB[4][2];
#pragma unroll
  for (int s = 0; s < 4; ++s)
#pragma unroll
    for (int t = 0; t < 2; ++t) {
      int g = s * 2 + lh;
      int mA = wr + t * 32 + l31;
      fOffA[s][t] = (mA * 8 + (g ^ (mA & 7))) * 16;
      int mB = wc + t * 32 + l31;
      fOffB[s][t] = (mB * 8 + (g ^ (mB & 7))) * 16;
    }

  f32x16 acc[2][2];
#pragma unroll
  for (int ti = 0; ti < 2; ++ti)
#pragma unroll
    for (int tj = 0; tj < 2; ++tj) acc[ti][tj] = (f32x16)0.0f;

  const _Float16* Aseg[3] = {P0, P1, P0};
  const _Float16* Bseg[3] = {P1, P0, P0};

  for (int pass = 0; pass < 3; ++pass) {
    if (pass == 2) {
      const float sc = 1.0f / 2048.0f;
#pragma unroll
      for (int ti = 0; ti < 2; ++ti)
#pragma unroll
        for (int tj = 0; tj < 2; ++tj)
#pragma unroll
          for (int r = 0; r < 16; ++r) acc[ti][tj][r] *= sc;
    }
    const _Float16* Ap = Aseg[pass];
    const _Float16* Bp = Bseg[pass];
    for (int c = 0; c < 4; ++c) {
      int kb = c * 64;
#pragma unroll
      for (int i = 0; i < 4; ++i)
        async_load16(Ap + rowOffA[i] + kb, AsB + ldsOff[i]);
#pragma unroll
      for (int i = 0; i < 4; ++i)
        async_load16(Bp + rowOffB[i] + kb, BsB + ldsOff[i]);
      __syncthreads();
#pragma unroll
      for (int s = 0; s < 4; ++s) {
        half8 af[2], bf[2];
#pragma unroll
        for (int t = 0; t < 2; ++t) {
          af[t] = *(const half8*)(AsB + fOffA[s][t]);
          bf[t] = *(const half8*)(BsB + fOffB[s][t]);
        }
#pragma unroll
        for (int ti = 0; ti < 2; ++ti)
#pragma unroll
          for (int tj = 0; tj < 2; ++tj)
            acc[ti][tj] = __builtin_amdgcn_mfma_f32_32x32x16_f16(
                af[ti], bf[tj], acc[ti][tj], 0, 0, 0);
      }
      __syncthreads();
    }
  }

  // epilogue: C/D col=lane&31, row=(reg&3)+8*(reg>>2)+4*lh
#pragma unroll
  for (int ti = 0; ti < 2; ++ti) {
    int gr0 = rowBase + wr + ti * 32 + 4 * lh;
#pragma unroll
    for (int tj = 0; tj < 2; ++tj) {
      int gc = colBase + wc + tj * 32 + l31;
#pragma unroll
      for (int r = 0; r < 16; ++r) {
        int gr = gr0 + (r & 3) + 8 * (r >> 2);
        C[(size_t)gr * N_NODES + gc] = acc[ti][tj][r];
      }
    }
  }
}

// ---------------------------------------------------------------------------
// Kernel 3: per-row top-(k+1) mask + relu, in place — exact R3 version
// (register-resident full-row scan; streaming at ~5.6 TB/s).
// ---------------------------------------------------------------------------
__global__ __launch_bounds__(256) void topk_kernel(
    float* __restrict__ C, const int* __restrict__ kptr) {
  constexpr int EPT = N_NODES / TPB;   // 40
  constexpr int NV4 = EPT / 4;         // 10
  __shared__ unsigned int lm[TPB];
  __shared__ unsigned int cu[CAP];
  __shared__ int ci[CAP];
  __shared__ unsigned int s_cnt, s_L31, s_Tu;
  __shared__ int s_Jcut;

  int tid = threadIdx.x;
  float* Crow = C + (size_t)blockIdx.x * N_NODES;
  unsigned int want = (unsigned int)(kptr[0] + 1);   // k+1

  unsigned int u[EPT];
  unsigned int lmax = 0u;
#pragma unroll
  for (int i = 0; i < NV4; ++i) {
    float4 v = *(const float4*)&Crow[(i * TPB + tid) * 4];
    float fv[4] = {v.x, v.y, v.z, v.w};
#pragma unroll
    for (int c = 0; c < 4; ++c) {
      unsigned int s = __float_as_uint(fv[c]);
      unsigned int m = (s & 0x80000000u) ? ~s : (s | 0x80000000u);
      u[i * 4 + c] = m;
      lmax = (m > lmax) ? m : lmax;
    }
  }
  lm[tid] = lmax;
  if (tid == 0) s_cnt = 0u;
  __syncthreads();

  // L31 = want-th largest of the 256 local maxima (broadcast LDS scan)
  {
    unsigned int r = 0;
    for (int j = 0; j < TPB; ++j) {
      unsigned int vj = lm[j];
      r += (vj > lmax) || (vj == lmax && j < tid);
    }
    if (r == want - 1) s_L31 = lmax;
  }
  __syncthreads();
  unsigned int L31 = s_L31;

  // gather candidates >= L31 (guaranteed >= want exist)
#pragma unroll
  for (int i = 0; i < EPT; ++i) {
    if (u[i] >= L31) {
      unsigned int pos = atomicAdd(&s_cnt, 1u);
      if (pos < CAP) {
        cu[pos] = u[i];
        ci[pos] = ((i / 4) * TPB + tid) * 4 + (i % 4);
      }
    }
  }
  __syncthreads();
  unsigned int c_total = s_cnt;

  if (c_total <= CAP) {
    for (unsigned int i = tid; i < c_total; i += TPB) {
      unsigned int ui = cu[i];
      int ii = ci[i];
      unsigned int r = 0;
      for (unsigned int j = 0; j < c_total; ++j) {
        unsigned int uj = cu[j];
        r += (uj > ui) || (uj == ui && ci[j] < ii);
      }
      if (r == want - 1) { s_Tu = ui; s_Jcut = ii; }
    }
    __syncthreads();
  } else {
    // degenerate fallback: bit-exact bisection on mapped value
    unsigned int lo = 0u, hi = 0xFFFFFFFFu;
    while (lo < hi) {
      unsigned int mid = lo + ((hi - lo) >> 1);
      unsigned int cnt = 0;
#pragma unroll
      for (int i = 0; i < EPT; ++i) cnt += (u[i] > mid) ? 1u : 0u;
      lm[tid] = cnt;
      __syncthreads();
      for (int o = TPB / 2; o > 0; o >>= 1) {
        if (tid < o) lm[tid] += lm[tid + o];
        __syncthreads();
      }
      unsigned int gcnt = lm[0];
      __syncthreads();
      if (gcnt < want) hi = mid; else lo = mid + 1u;
    }
    unsigned int Tu = lo;
    unsigned int cnt = 0;
#pragma unroll
    for (int i = 0; i < EPT; ++i) cnt += (u[i] > Tu) ? 1u : 0u;
    lm[tid] = cnt;
    __syncthreads();
    for (int o = TPB / 2; o > 0; o >>= 1) {
      if (tid < o) lm[tid] += lm[tid + o];
      __syncthreads();
    }
    unsigned int need = want - lm[0];
    __syncthreads();
    int jlo = 0, jhi = N_NODES - 1;
    while (jlo < jhi) {
      int jmid = (jlo + jhi) >> 1;
      unsigned int cc = 0;
#pragma unroll
      for (int i = 0; i < EPT; ++i) {
        int jj = ((i / 4) * TPB + tid) * 4 + (i % 4);
        cc += (u[i] == Tu && jj <= jmid) ? 1u : 0u;
      }
      lm[tid] = cc;
      __syncthreads();
      for (int o = TPB / 2; o > 0; o >>= 1) {
        if (tid < o) lm[tid] += lm[tid + o];
        __syncthreads();
      }
      unsigned int tot = lm[0];
      __syncthreads();
      if (tot >= need) jhi = jmid; else jlo = jmid + 1;
    }
    if (tid == 0) { s_Tu = Tu; s_Jcut = jlo; }
    __syncthreads();
  }

  unsigned int Tu = s_Tu;
  int Jcut = s_Jcut;

#pragma unroll
  for (int i = 0; i < NV4; ++i) {
    float out[4];
#pragma unroll
    for (int c = 0; c < 4; ++c) {
      unsigned int m = u[i * 4 + c];
      int j = (i * TPB + tid) * 4 + c;
      bool keep = (m > Tu) || (m == Tu && j <= Jcut);
      float v = __uint_as_float((m & 0x80000000u) ? (m ^ 0x80000000u) : ~m);
      out[c] = (keep && v > 0.0f) ? v : 0.0f;
    }
    *(float4*)&Crow[(i * TPB + tid) * 4] =
        make_float4(out[0], out[1], out[2], out[3]);
  }
}

// ---------------------------------------------------------------------------
extern "C" void kernel_launch(void* const* d_in, const int* in_sizes, int n_in,
                              void* d_out, int out_size, void* d_ws, size_t ws_size,
                              hipStream_t stream) {
  const float* F  = (const float*)d_in[0];
  const float* w1 = (const float*)d_in[1];
  const float* w2 = (const float*)d_in[2];
  const int*   kp = (const int*)d_in[3];
  float* C = (float*)d_out;
  _Float16* P0 = (_Float16*)d_ws;                    // N*D fp16 = 5.24 MB
  _Float16* P1 = P0 + (size_t)N_NODES * DIM;         // N*D fp16 = 5.24 MB

  norm_split_kernel<<<N_NODES / 4, TPB, 0, stream>>>(F, w1, w2, P0, P1);

  dim3 grid(N_NODES / 128, N_NODES / 128);           // 80 x 80
  gemm_mfma_kernel<<<grid, 256, 0, stream>>>(P0, P1, C);

  topk_kernel<<<N_NODES, TPB, 0, stream>>>(C, kp);
}